// Round 22
// baseline (118.264 us; speedup 1.0000x reference)
//
#include <hip/hip_runtime.h>
#include <math.h>

#define B_   8
#define C_   64
#define CK_  8
#define L_   4096
#define LOG2E 1.44269504088896f

typedef __attribute__((ext_vector_type(8))) __bf16 bf16x8;
typedef __attribute__((ext_vector_type(4))) __bf16 bf16x4;
typedef __attribute__((ext_vector_type(4))) float  f32x4;

// ---------------- Kernel 1: QKV projection -> bf16 ----------------
// r20-verified math/layout, split 2x along output channels for occupancy:
// grid B*64*2. Block h=0: v-channels 0-31 + q (log2e-prescaled);
// h=1: v-channels 32-63 + k. Per-block LDS 44->28.5 KB, grid 512->1024
// (2->4 blocks/CU, 8->16 waves/CU). vpack/qo/ko layouts byte-identical:
// cb = 2h + (g>>2); (8h+g)&3 == g&3. x tile staged by both halves.
__global__ __launch_bounds__(256) void qkv_kernel(
    const float* __restrict__ x,
    const float* __restrict__ Wq, const float* __restrict__ bq,
    const float* __restrict__ Wk, const float* __restrict__ bk,
    const float* __restrict__ Wv, const float* __restrict__ bv,
    __bf16* __restrict__ qo, __bf16* __restrict__ ko, __bf16* __restrict__ vpack)
{
    __shared__ float LWqk[CK_ * C_];    // q-weights (h=0, prescaled) or k-weights (h=1)
    __shared__ float LWv[32 * C_];      // this half's 32 v rows, row-major
    __shared__ float LX[64][68];        // x tile [c][l], pad 68
    __shared__ __bf16 Lqs[64 * 8];      // q (h=0) or k (h=1) gather buffer

    const int tid = threadIdx.x;
    const int idx = blockIdx.x;
    const int b  = idx >> 7;
    const int t  = (idx >> 1) & 63;
    const int h  = idx & 1;
    const int l0 = t << 6;

    if (tid < 128) {
        float4 a = h ? ((const float4*)Wk)[tid] : ((const float4*)Wq)[tid];
        if (!h) { a.x *= LOG2E; a.y *= LOG2E; a.z *= LOG2E; a.w *= LOG2E; }
        ((float4*)LWqk)[tid] = a;
    }
    {   // stage this half's 32 Wv rows: 512 float4s
        const float4* wv4 = (const float4*)Wv + (size_t)h * 512;
        ((float4*)LWv)[tid]       = wv4[tid];
        ((float4*)LWv)[tid + 256] = wv4[tid + 256];
    }
    {   // stage x tile (all 64 channels)
        const int c = tid >> 2, part = tid & 3;
        const float* xrow = x + ((size_t)b * C_ + c) * L_ + l0 + part * 16;
        float4* dst = (float4*)&LX[c][part * 16];
        #pragma unroll
        for (int u = 0; u < 4; ++u) dst[u] = ((const float4*)xrow)[u];
    }
    __syncthreads();

    const int lg = tid & 15;
    const int g  = tid >> 4;        // [0,8): v-channels 32h+4g..+3 ; [8,16): q/k channel g-8

    if (g < 8) {
        float va[4][4];
        #pragma unroll
        for (int j = 0; j < 4; ++j) {
            float bb = bv[32 * h + 4 * g + j];
            va[j][0] = bb; va[j][1] = bb; va[j][2] = bb; va[j][3] = bb;
        }
        #pragma unroll 4
        for (int c4 = 0; c4 < 16; ++c4) {
            float4 xv[4];
            #pragma unroll
            for (int u = 0; u < 4; ++u)
                xv[u] = *(const float4*)&LX[4 * c4 + u][lg * 4];
            #pragma unroll
            for (int j = 0; j < 4; ++j) {
                float4 wv = ((const float4*)(LWv + (4 * g + j) * C_))[c4];
                float* a = va[j];
                a[0]=fmaf(wv.x,xv[0].x,a[0]); a[1]=fmaf(wv.x,xv[0].y,a[1]); a[2]=fmaf(wv.x,xv[0].z,a[2]); a[3]=fmaf(wv.x,xv[0].w,a[3]);
                a[0]=fmaf(wv.y,xv[1].x,a[0]); a[1]=fmaf(wv.y,xv[1].y,a[1]); a[2]=fmaf(wv.y,xv[1].z,a[2]); a[3]=fmaf(wv.y,xv[1].w,a[3]);
                a[0]=fmaf(wv.z,xv[2].x,a[0]); a[1]=fmaf(wv.z,xv[2].y,a[1]); a[2]=fmaf(wv.z,xv[2].z,a[2]); a[3]=fmaf(wv.z,xv[2].w,a[3]);
                a[0]=fmaf(wv.w,xv[3].x,a[0]); a[1]=fmaf(wv.w,xv[3].y,a[1]); a[2]=fmaf(wv.w,xv[3].z,a[2]); a[3]=fmaf(wv.w,xv[3].w,a[3]);
            }
        }
        // vpack stores, pair-interleaved layout (r17/r20-verified)
        const int T = t >> 1, p = t & 1;
        __bf16* vt = vpack + ((size_t)(b * 32 + T)) * 8192 + p * 4;
        const int cb = 2 * h + (g >> 2);
        const int sg = lg >> 2;
        const int qd = lg & 3;
        #pragma unroll
        for (int j = 0; j < 4; ++j) {
            bf16x4 vv;
            vv[0]=(__bf16)va[j][0]; vv[1]=(__bf16)va[j][1]; vv[2]=(__bf16)va[j][2]; vv[3]=(__bf16)va[j][3];
            *(bf16x4*)(vt + (size_t)((cb * 4 + sg) * 512 + (qd * 16 + (g & 3) * 4 + j) * 8)) = vv;
        }
    } else {
        const int kc = g - 8;
        float qk[4];
        {
            float bb = h ? bk[kc] : bq[kc] * LOG2E;
            qk[0] = bb; qk[1] = bb; qk[2] = bb; qk[3] = bb;
        }
        const float* wqk = LWqk + kc * C_;
        #pragma unroll 4
        for (int c4 = 0; c4 < 16; ++c4) {
            float4 xv[4];
            #pragma unroll
            for (int u = 0; u < 4; ++u)
                xv[u] = *(const float4*)&LX[4 * c4 + u][lg * 4];
            float4 wv = ((const float4*)wqk)[c4];
            qk[0]=fmaf(wv.x,xv[0].x,qk[0]); qk[1]=fmaf(wv.x,xv[0].y,qk[1]); qk[2]=fmaf(wv.x,xv[0].z,qk[2]); qk[3]=fmaf(wv.x,xv[0].w,qk[3]);
            qk[0]=fmaf(wv.y,xv[1].x,qk[0]); qk[1]=fmaf(wv.y,xv[1].y,qk[1]); qk[2]=fmaf(wv.y,xv[1].z,qk[2]); qk[3]=fmaf(wv.y,xv[1].w,qk[3]);
            qk[0]=fmaf(wv.z,xv[2].x,qk[0]); qk[1]=fmaf(wv.z,xv[2].y,qk[1]); qk[2]=fmaf(wv.z,xv[2].z,qk[2]); qk[3]=fmaf(wv.z,xv[2].w,qk[3]);
            qk[0]=fmaf(wv.w,xv[3].x,qk[0]); qk[1]=fmaf(wv.w,xv[3].y,qk[1]); qk[2]=fmaf(wv.w,xv[3].z,qk[2]); qk[3]=fmaf(wv.w,xv[3].w,qk[3]);
        }
        #pragma unroll
        for (int u = 0; u < 4; ++u)
            Lqs[(lg * 4 + u) * 8 + kc] = (__bf16)qk[u];
    }
    __syncthreads();
    if (tid < 64) {
        __bf16* dst = (h ? ko : qo) + ((size_t)b * L_ + l0 + tid) * 8;
        *(bf16x8*)dst = *(bf16x8*)(Lqs + tid * 8);
    }
}

// ---------------- Kernel 2: fused attention ------------------------------
// Byte-identical to the r20 hardware-verified version (attn ~40us, VGPR 60,
// exp2-prescale, pair-interleaved V, q staged via LDS, XCD swizzle).
__global__ __launch_bounds__(512, 4) void attn_kernel(
    const __bf16* __restrict__ q, const __bf16* __restrict__ kT,
    const __bf16* __restrict__ VP, const float* __restrict__ x,
    const float* __restrict__ gamma_p, float* __restrict__ out)
{
    __shared__ __bf16 Lv[2][16384];     // 64 KB: [buf][h*8192 + row*512 + lane*8 (+p*4)]
    __shared__ __bf16 Lq[2][2][1024];   // 8 KB:  [buf][lh][part*512 + srow*8]
    __shared__ float  csA[8][16];

    const int tid  = threadIdx.x;
    const int w    = tid >> 6;
    const int lane = tid & 63;
    const int quad = lane >> 4;
    const int l16  = lane & 15;
    const int wh   = w & 3;
    const int lh   = w >> 2;
    const int wg   = blockIdx.x;
    const int b    = wg & 7;            // XCD swizzle
    const int mb   = wg >> 3;
    const int m0   = mb << 6;

    const __bf16* vp2 = VP + (size_t)b * 262144;
    const __bf16* qb  = q  + (size_t)b * L_ * CK_;

    bf16x8 kf = {};
    if (quad == 0) kf = *(const bf16x8*)(kT + ((size_t)b * L_ + m0 + wh * 16 + l16) * CK_);

    // V staging shares: u = w*4+k in [0,32): h = u>>4 (lh-half), s16 = u&15 (row)
    const __bf16* gk[4];
    int ok[4];
    #pragma unroll
    for (int k = 0; k < 4; ++k) {
        const int u = w * 4 + k, h = u >> 4, s16 = u & 15;
        gk[k] = vp2 + (size_t)(h * 16) * 8192 + s16 * 512 + lane * 8;
        ok[k] = h * 8192 + s16 * 512 + lane * 8;
    }
    // q staging share (waves 0-3): lh_q = w>>1, part = w&1; row = lane.
    const __bf16* gq = qb + (size_t)((w >> 1) * 2048 + (w & 1) * 64 + lane) * 8;
    const int oq = (w >> 1) * 1024 + (w & 1) * 512 + lane * 8;

    f32x4 acc[4] = {};
    float csum = 0.f;
    bf16x8 r[4], rq;

    // prologue: stage iter 0 (V + q) into buf0
    #pragma unroll
    for (int k = 0; k < 4; ++k) r[k] = *(const bf16x8*)gk[k];
    if (w < 4) rq = *(const bf16x8*)gq;
    #pragma unroll
    for (int k = 0; k < 4; ++k) *(bf16x8*)(&Lv[0][0] + ok[k]) = r[k];
    if (w < 4) *(bf16x8*)(&Lq[0][0][0] + oq) = rq;

    for (int i = 0; i < 16; ++i) {
        __syncthreads();    // publish buf i&1; all reads of buf (i+1)&1 done

        if (i < 15) {       // issue next-iter loads early (land under compute)
            #pragma unroll
            for (int k = 0; k < 4; ++k)
                r[k] = *(const bf16x8*)(gk[k] + (size_t)(i + 1) * 8192);
            if (w < 4) rq = *(const bf16x8*)(gq + (size_t)(i + 1) * 1024);
        }

        const __bf16* Lqh = &Lq[i & 1][lh][0];
        const __bf16* Lb  = &Lv[i & 1][lh * 8192];
        #pragma unroll
        for (int sg = 0; sg < 4; ++sg) {
            bf16x8 qA = *(const bf16x8*)(Lqh + (sg * 16 + l16) * 8);
            bf16x8 qB = *(const bf16x8*)(Lqh + 512 + (sg * 16 + l16) * 8);
            f32x4 svA = __builtin_amdgcn_mfma_f32_16x16x32_bf16(qA, kf, (f32x4){0.f,0.f,0.f,0.f}, 0, 0, 0);
            f32x4 svB = __builtin_amdgcn_mfma_f32_16x16x32_bf16(qB, kf, (f32x4){0.f,0.f,0.f,0.f}, 0, 0, 0);

            const float eA0 = __builtin_amdgcn_exp2f(svA[0]);
            const float eA1 = __builtin_amdgcn_exp2f(svA[1]);
            const float eA2 = __builtin_amdgcn_exp2f(svA[2]);
            const float eA3 = __builtin_amdgcn_exp2f(svA[3]);
            const float eB0 = __builtin_amdgcn_exp2f(svB[0]);
            const float eB1 = __builtin_amdgcn_exp2f(svB[1]);
            const float eB2 = __builtin_amdgcn_exp2f(svB[2]);
            const float eB3 = __builtin_amdgcn_exp2f(svB[3]);
            csum += ((eA0 + eA1) + (eA2 + eA3)) + ((eB0 + eB1) + (eB2 + eB3));

            bf16x8 p8;
            p8[0]=(__bf16)eA0; p8[1]=(__bf16)eA1; p8[2]=(__bf16)eA2; p8[3]=(__bf16)eA3;
            p8[4]=(__bf16)eB0; p8[5]=(__bf16)eB1; p8[6]=(__bf16)eB2; p8[7]=(__bf16)eB3;

            #pragma unroll
            for (int cb = 0; cb < 4; ++cb) {
                bf16x8 a8 = *(const bf16x8*)(Lb + (size_t)((cb * 4 + sg) * 512 + lane * 8));
                acc[cb] = __builtin_amdgcn_mfma_f32_16x16x32_bf16(a8, p8, acc[cb], 0, 0, 0);
            }
        }

        if (i < 15) {       // write-late into the other buffer
            const int nb = (i + 1) & 1;
            #pragma unroll
            for (int k = 0; k < 4; ++k)
                *(bf16x8*)(&Lv[nb][0] + ok[k]) = r[k];
            if (w < 4) *(bf16x8*)(&Lq[nb][0][0] + oq) = rq;
        }
    }

    // ---- epilogue: reduce lh=1 into lh=0, normalize, residual ----
    // Sc = first 16 KB of Lv buf0; last iter (15) read buf1 only.
    float* Sc = (float*)&Lv[0][0];
    if (lh == 1) {
        #pragma unroll
        for (int cb = 0; cb < 4; ++cb)
            #pragma unroll
            for (int r2 = 0; r2 < 4; ++r2)
                Sc[(wh * 64 + cb * 16 + quad * 4 + r2) * 16 + l16] = acc[cb][r2];
    }
    csum += __shfl_xor(csum, 16);
    csum += __shfl_xor(csum, 32);
    if (quad == 0) csA[w][l16] = csum;
    __syncthreads();

    if (lh == 0) {
        const float rinv = gamma_p[0] / (csA[wh][l16] + csA[wh + 4][l16]);
        #pragma unroll
        for (int cb = 0; cb < 4; ++cb) {
            #pragma unroll
            for (int r2 = 0; r2 < 4; ++r2) {
                const int c = cb * 16 + quad * 4 + r2;
                const float vsum = acc[cb][r2] + Sc[(wh * 64 + c) * 16 + l16];
                const size_t idx = ((size_t)(b * 64 + c)) * L_ + m0 + wh * 16 + l16;
                out[idx] = fmaf(rinv, vsum, x[idx]);
            }
        }
    }
}

extern "C" void kernel_launch(void* const* d_in, const int* in_sizes, int n_in,
                              void* d_out, int out_size, void* d_ws, size_t ws_size,
                              hipStream_t stream) {
    const float* x  = (const float*)d_in[0];
    const float* Wq = (const float*)d_in[1];
    const float* bq = (const float*)d_in[2];
    const float* Wk = (const float*)d_in[3];
    const float* bk = (const float*)d_in[4];
    const float* Wv = (const float*)d_in[5];
    const float* bv = (const float*)d_in[6];
    const float* gm = (const float*)d_in[7];
    float* out = (float*)d_out;

    __bf16* ws    = (__bf16*)d_ws;
    __bf16* qo    = ws;                         // 262144 bf16
    __bf16* ko    = ws + 262144;                // 262144 bf16
    __bf16* vpack = ws + 524288;                // 2097152 bf16

    qkv_kernel<<<dim3(B_ * 64 * 2), dim3(256), 0, stream>>>(
        x, Wq, bq, Wk, bk, Wv, bv, qo, ko, vpack);
    attn_kernel<<<dim3(B_ * 64), dim3(512), 0, stream>>>(
        qo, ko, vpack, x, gm, out);
}